// Round 2
// baseline (232.853 us; speedup 1.0000x reference)
//
#include <hip/hip_runtime.h>
#include <cmath>

#define LOG2E 1.4426950408889634f

typedef __attribute__((ext_vector_type(8))) __bf16 bf16x8;
typedef __attribute__((ext_vector_type(4))) float f32x4;
typedef __attribute__((ext_vector_type(4))) float float4v;
typedef __attribute__((ext_vector_type(8))) unsigned short ushort8;

__device__ __forceinline__ unsigned short f2bf(float f) {
  unsigned int u = __builtin_bit_cast(unsigned int, f);
  u += 0x7fffu + ((u >> 16) & 1u);   // RNE
  return (unsigned short)(u >> 16);
}

// raw barrier that does NOT drain vmcnt (keeps async prefetch in flight)
__device__ __forceinline__ void barrier_lgkm() {
  asm volatile("s_waitcnt lgkmcnt(0)" ::: "memory");
  __builtin_amdgcn_s_barrier();
  __builtin_amdgcn_sched_barrier(0);
}

// async global->LDS, 16B per lane; LDS dest = wave-uniform base + lane*16
__device__ __forceinline__ void gload_lds16(const unsigned short* g, unsigned short* l) {
  __builtin_amdgcn_global_load_lds(
      (const __attribute__((address_space(1))) unsigned int*)(const void*)g,
      (__attribute__((address_space(3))) unsigned int*)(void*)l, 16, 0, 0);
}

// ---------- kernel 1: Wt[w][n][k] = bf16(W_w[k][n] * (w==0 ? LOG2E/16 : 1)) ----------
__global__ __launch_bounds__(256) void prep_w_kernel(
    const float* __restrict__ Wq, const float* __restrict__ Wk,
    const float* __restrict__ Wv, unsigned short* __restrict__ Wt) {
  const int w = blockIdx.y, n = blockIdx.x, k = threadIdx.x;
  const float* W = (w == 0) ? Wq : ((w == 1) ? Wk : Wv);
  const float s = (w == 0) ? (LOG2E / 16.0f) : 1.0f;
  Wt[w * 65536 + n * 256 + k] = f2bf(W[k * 256 + n] * s);
}

// ---------- kernel 2: fused q/k/v projection (x read once) ----------
__global__ __launch_bounds__(256) void proj_kernel(
    const float* __restrict__ x, const unsigned short* __restrict__ Wt,
    const float* __restrict__ bq, const float* __restrict__ bk,
    const float* __restrict__ bv,
    unsigned short* __restrict__ q_o, unsigned short* __restrict__ k_o,
    unsigned short* __restrict__ vt_o) {
  const int mt = blockIdx.x;           // 256 m-tiles of 64 rows
  const int tid = threadIdx.x;
  const int wid = tid >> 6, lane = tid & 63, g = (lane >> 4) & 3, c = lane & 15;
  const int row_base = mt * 64 + wid * 16;

  // A fragments: x rows (fp32 -> bf16), lane: row = c, k = s*32 + g*8 + j
  bf16x8 a[8];
  const float* xr = x + (size_t)(row_base + c) * 256;
#pragma unroll
  for (int s = 0; s < 8; ++s) {
    const float4v v0 = *(const float4v*)(xr + s * 32 + g * 8);
    const float4v v1 = *(const float4v*)(xr + s * 32 + g * 8 + 4);
    union { bf16x8 v; unsigned short u[8]; } t;
#pragma unroll
    for (int j = 0; j < 4; ++j) { t.u[j] = f2bf(v0[j]); t.u[4 + j] = f2bf(v1[j]); }
    a[s] = t.v;
  }

  for (int w = 0; w < 3; ++w) {
    const float* bias = (w == 0) ? bq : ((w == 1) ? bk : bv);
    const float bscale = (w == 0) ? (LOG2E / 16.0f) : 1.0f;
    const unsigned short* wtb = Wt + w * 65536;
#pragma unroll
    for (int nf = 0; nf < 16; ++nf) {
      f32x4 acc = (f32x4){0.f, 0.f, 0.f, 0.f};
      const unsigned short* wr = wtb + (size_t)(nf * 16 + c) * 256;
#pragma unroll
      for (int s = 0; s < 8; ++s) {
        bf16x8 b = *(const bf16x8*)(wr + s * 32 + g * 8);
        acc = __builtin_amdgcn_mfma_f32_16x16x32_bf16(a[s], b, acc, 0, 0, 0);
      }
      const float bvl = bias[nf * 16 + c] * bscale;
#pragma unroll
      for (int r = 0; r < 4; ++r) {
        const int row = row_base + g * 4 + r;
        const unsigned short ov = f2bf(acc[r] + bvl);
        if (w == 0) {
          q_o[(size_t)row * 256 + nf * 16 + c] = ov;
        } else if (w == 1) {
          k_o[(size_t)row * 256 + nf * 16 + c] = ov;
        } else {
          const int b_ = row >> 12, s_ = row & 4095;
          vt_o[((size_t)b_ * 256 + nf * 16 + c) * 4096 + s_] = ov;
        }
      }
    }
  }
}

// ---------- kernel 3: causal flash attention, merged pair + async dbuf staging ----------
// grid 256; bid -> (batch = (bid&7)>>1, pi = 2*(bid>>3) + (bid&1)) so each XCD
// serves one batch's K/V stream. Block handles q-tiles pi and 127-pi over ONE
// shared kv sweep (two register states); tile0 active while t <= pi>>1.
__global__ __launch_bounds__(256, 1) void attn_kernel(
    const unsigned short* __restrict__ qg, const unsigned short* __restrict__ kg,
    const unsigned short* __restrict__ vtg, float* __restrict__ out) {
  __shared__ unsigned short Klds[2][64 * 256];   // double-buffered, swizzled image
  __shared__ unsigned short Vlds[2][256 * 64];
  __shared__ unsigned short Plds[2][32 * 64];    // per-tile slot
  __shared__ float smax[2][2][2][16];            // [slot][wq][wk][row]
  __shared__ float ssum[2][2][2][16];

  const int tid = threadIdx.x;
  const int wid = tid >> 6, lane = tid & 63, g = (lane >> 4) & 3, c = lane & 15;
  const int wq = wid >> 1, wk = wid & 1;
  const int bid = blockIdx.x;
  const int b = (bid & 7) >> 1;
  const int pi = ((bid >> 3) << 1) | (bid & 1);

  const unsigned short* qb = qg + (size_t)b * 4096 * 256;
  const unsigned short* kb = kg + (size_t)b * 4096 * 256;
  const unsigned short* vb = vtg + (size_t)b * 256 * 4096;
  float* outb = out + (size_t)b * 4096 * 256;

  const int qi0 = pi, qi1 = 127 - pi;
  const int q00 = qi0 * 32, q01 = qi1 * 32;
  const int t0max = qi0 >> 1;
  const int T = (qi1 >> 1) + 1;

  // Pre-swizzled global source offsets for global_load_lds (LDS dest linear).
  // K: linear u = (wid*8+i)*64 + lane -> kr = u>>5, c8 = (u&31)^(kr&7)
  // V: d = u>>3, c8 = (u&7)^(d&7)
  int koff[8], voff[8];
#pragma unroll
  for (int i = 0; i < 8; ++i) {
    const int kr = wid * 16 + i * 2 + (lane >> 5);
    const int c8 = (lane & 31) ^ (kr & 7);
    koff[i] = kr * 256 + c8 * 8;
    const int d = wid * 64 + i * 8 + (lane >> 3);
    const int c8v = (lane & 7) ^ (d & 7);
    voff[i] = d * 4096 + c8v * 8;
  }

  auto stage = [&](int bufn, int t) {
    const unsigned short* kp = kb + t * (64 * 256);
    const unsigned short* vp = vb + t * 64;
#pragma unroll
    for (int i = 0; i < 8; ++i)
      gload_lds16(kp + koff[i], &Klds[bufn][(wid * 8 + i) * 512]);
#pragma unroll
    for (int i = 0; i < 8; ++i)
      gload_lds16(vp + voff[i], &Vlds[bufn][(wid * 8 + i) * 512]);
  };

  // Q fragments for both tiles: lane row = c, k = s*32 + g*8 + j
  bf16x8 aq0[8], aq1[8];
  {
    const unsigned short* qr0 = qb + (size_t)(q00 + wq * 16 + c) * 256;
    const unsigned short* qr1 = qb + (size_t)(q01 + wq * 16 + c) * 256;
#pragma unroll
    for (int s = 0; s < 8; ++s) {
      aq0[s] = *(const bf16x8*)(qr0 + s * 32 + g * 8);
      aq1[s] = *(const bf16x8*)(qr1 + s * 32 + g * 8);
    }
  }

  float m0[4], l0[4], m1[4], l1[4];
  f32x4 o0[8], o1[8];
#pragma unroll
  for (int r = 0; r < 4; ++r) { m0[r] = -INFINITY; l0[r] = 0.f; m1[r] = -INFINITY; l1[r] = 0.f; }
#pragma unroll
  for (int fd = 0; fd < 8; ++fd) {
    o0[fd] = (f32x4){0.f, 0.f, 0.f, 0.f};
    o1[fd] = (f32x4){0.f, 0.f, 0.f, 0.f};
  }

  auto tile_compute = [&](bf16x8 (&aq)[8], f32x4 (&o)[8], float (&m)[4], float (&l)[4],
                          const int q0, const bool diag, const int slot,
                          const int bufn, const int kv0) {
    // ---- QK^T: S[q 16][k 32] for this (wq,wk) quarter ----
    f32x4 sc[2];
    sc[0] = (f32x4){0.f, 0.f, 0.f, 0.f};
    sc[1] = (f32x4){0.f, 0.f, 0.f, 0.f};
#pragma unroll
    for (int f = 0; f < 2; ++f) {
      const int kr = wk * 32 + f * 16 + c;
      const int rowoff = kr * 256, sw = (kr & 7) << 3;
#pragma unroll
      for (int s = 0; s < 8; ++s) {
        bf16x8 bfr = *(const bf16x8*)(&Klds[bufn][(rowoff + s * 32 + g * 8) ^ sw]);
        sc[f] = __builtin_amdgcn_mfma_f32_16x16x32_bf16(aq[s], bfr, sc[f], 0, 0, 0);
      }
    }

    // ---- mask + per-row partial max (scores already in exp2 domain) ----
    float pm[4];
#pragma unroll
    for (int r = 0; r < 4; ++r) pm[r] = -INFINITY;
#pragma unroll
    for (int f = 0; f < 2; ++f) {
      const int kcol = kv0 + wk * 32 + f * 16 + c;
#pragma unroll
      for (int r = 0; r < 4; ++r) {
        float v = sc[f][r];
        if (diag && kcol > q0 + wq * 16 + g * 4 + r) v = -INFINITY;
        sc[f][r] = v;
        pm[r] = fmaxf(pm[r], v);
      }
    }
#pragma unroll
    for (int r = 0; r < 4; ++r) {
      pm[r] = fmaxf(pm[r], __shfl_xor(pm[r], 1));
      pm[r] = fmaxf(pm[r], __shfl_xor(pm[r], 2));
      pm[r] = fmaxf(pm[r], __shfl_xor(pm[r], 4));
      pm[r] = fmaxf(pm[r], __shfl_xor(pm[r], 8));
    }
    if (c == 0) {
#pragma unroll
      for (int r = 0; r < 4; ++r) smax[slot][wq][wk][g * 4 + r] = pm[r];
    }
    barrier_lgkm();  // partial maxes visible (vmcnt untouched)

    // ---- combine max, exp, P write, partial row-sums ----
    float alpha[4], ps[4];
#pragma unroll
    for (int r = 0; r < 4; ++r) {
      const float mn = fmaxf(
          m[r], fmaxf(smax[slot][wq][0][g * 4 + r], smax[slot][wq][1][g * 4 + r]));
      alpha[r] = __builtin_amdgcn_exp2f(m[r] - mn);
      m[r] = mn;
      ps[r] = 0.f;
    }
#pragma unroll
    for (int f = 0; f < 2; ++f) {
      const int kc = wk * 32 + f * 16 + c;
#pragma unroll
      for (int r = 0; r < 4; ++r) {
        const float p = __builtin_amdgcn_exp2f(sc[f][r] - m[r]);
        ps[r] += p;
        const int ql = wq * 16 + g * 4 + r;
        Plds[slot][(ql * 64 + kc) ^ ((ql & 7) << 3)] = f2bf(p);
      }
    }
#pragma unroll
    for (int r = 0; r < 4; ++r) {
      ps[r] += __shfl_xor(ps[r], 1);
      ps[r] += __shfl_xor(ps[r], 2);
      ps[r] += __shfl_xor(ps[r], 4);
      ps[r] += __shfl_xor(ps[r], 8);
    }
    if (c == 0) {
#pragma unroll
      for (int r = 0; r < 4; ++r) ssum[slot][wq][wk][g * 4 + r] = ps[r];
    }
    barrier_lgkm();  // P tile + partial sums visible

    // ---- l update + O rescale ----
#pragma unroll
    for (int r = 0; r < 4; ++r)
      l[r] = l[r] * alpha[r] + ssum[slot][wq][0][g * 4 + r] + ssum[slot][wq][1][g * 4 + r];
#pragma unroll
    for (int fd = 0; fd < 8; ++fd)
#pragma unroll
      for (int r = 0; r < 4; ++r) o[fd][r] *= alpha[r];

    // ---- PV: O[q 16][d 128-half] += P[q][k64] @ V[k64][d] ----
    bf16x8 pa[2];
    {
      const int ql = wq * 16 + c;
      const int sw = (ql & 7) << 3;
#pragma unroll
      for (int s2 = 0; s2 < 2; ++s2)
        pa[s2] = *(const bf16x8*)(&Plds[slot][(ql * 64 + s2 * 32 + g * 8) ^ sw]);
    }
#pragma unroll
    for (int fd = 0; fd < 8; ++fd) {
      const int dl = wk * 128 + fd * 16 + c;
      const int rowoff = dl * 64, sw = (dl & 7) << 3;
#pragma unroll
      for (int s2 = 0; s2 < 2; ++s2) {
        bf16x8 bfr = *(const bf16x8*)(&Vlds[bufn][(rowoff + s2 * 32 + g * 8) ^ sw]);
        o[fd] = __builtin_amdgcn_mfma_f32_16x16x32_bf16(pa[s2], bfr, o[fd], 0, 0, 0);
      }
    }
  };

  // ---- pipelined kv sweep ----
  stage(0, 0);
  for (int t = 0; t < T; ++t) {
    const int bufn = t & 1;
    __syncthreads();                       // drains vmcnt: buf[t] staged; buf[t^1] free
    if (t + 1 < T) stage(bufn ^ 1, t + 1); // prefetch overlaps this tile's compute
    const int kv0 = t * 64;
    if (t <= t0max)
      tile_compute(aq0, o0, m0, l0, q00, t == t0max, 0, bufn, kv0);
    tile_compute(aq1, o1, m1, l1, q01, t == T - 1, 1, bufn, kv0);
  }

  // ---- epilogue: O / l -> out (fp32) ----
  auto epilogue = [&](f32x4 (&o)[8], float (&l)[4], int q0) {
#pragma unroll
    for (int r = 0; r < 4; ++r) {
      const float inv = 1.0f / l[r];
      const int qrow = q0 + wq * 16 + g * 4 + r;
#pragma unroll
      for (int fd = 0; fd < 8; ++fd)
        outb[(size_t)qrow * 256 + wk * 128 + fd * 16 + c] = o[fd][r] * inv;
    }
  };
  epilogue(o0, l0, q00);
  epilogue(o1, l1, q01);
}

extern "C" void kernel_launch(void* const* d_in, const int* in_sizes, int n_in,
                              void* d_out, int out_size, void* d_ws, size_t ws_size,
                              hipStream_t stream) {
  (void)in_sizes; (void)n_in; (void)out_size; (void)ws_size;
  const float* x  = (const float*)d_in[0];
  const float* Wq = (const float*)d_in[1];
  const float* bq = (const float*)d_in[2];
  const float* Wk = (const float*)d_in[3];
  const float* bk = (const float*)d_in[4];
  const float* Wv = (const float*)d_in[5];
  const float* bv = (const float*)d_in[6];
  float* out = (float*)d_out;

  unsigned short* qs  = (unsigned short*)d_ws;                 // [4][4096][256] bf16
  unsigned short* ks  = qs  + (size_t)16384 * 256;             // [4][4096][256] bf16
  unsigned short* vts = ks  + (size_t)16384 * 256;             // [4][256][4096] bf16 (V^T)
  unsigned short* Wt  = vts + (size_t)16384 * 256;             // [3][256][256]  bf16 (W^T)

  prep_w_kernel<<<dim3(256, 3), 256, 0, stream>>>(Wq, Wk, Wv, Wt);
  proj_kernel<<<256, 256, 0, stream>>>(x, Wt, bq, bk, bv, qs, ks, vts);
  attn_kernel<<<256, 256, 0, stream>>>(qs, ks, vts, out);
}